// Round 2
// baseline (630.746 us; speedup 1.0000x reference)
//
#include <hip/hip_runtime.h>
#include <stdint.h>

#define B_ 8
#define S_ 2048
#define D_ 768
#define FF_ 3072
#define E_ 8
#define C_ 384

typedef unsigned short u16;
typedef float  v4f  __attribute__((ext_vector_type(4)));
typedef __bf16 bf8v __attribute__((ext_vector_type(8)));

__device__ __forceinline__ u16 f2bf(float f) {
  union { float f; uint32_t i; } v; v.f = f;
  uint32_t u = v.i;
  return (u16)((u + 0x7FFFu + ((u >> 16) & 1u)) >> 16);   // RNE
}

// async global->LDS, 16B per lane. LDS dest must be wave-uniform base + lane*16.
typedef const __attribute__((address_space(1))) void* gas1_t;
typedef __attribute__((address_space(3))) void* las3_t;
__device__ __forceinline__ void gl_lds16(const void* g, void* l) {
  __builtin_amdgcn_global_load_lds((gas1_t)g, (las3_t)l, 16, 0, 0);
}

// XCD-aware bijective block swizzle (m204 variant): XCD k gets a contiguous
// chunk of logical tile ids. HW round-robins hardware wg id across 8 XCDs.
__device__ __forceinline__ int xcd_swz(int flat, int nwg) {
  int q = nwg >> 3, r = nwg & 7;
  int xcd = flat & 7, off = flat >> 3;
  return (xcd < r ? xcd * (q + 1) : r * (q + 1) + (xcd - r) * q) + off;
}

// ---------------- weight transpose+convert for expert chunk [e0, e0+ne)
__global__ __launch_bounds__(256) void k_transpose(const float* __restrict__ Wi,
                                                   const float* __restrict__ Wo,
                                                   u16* __restrict__ WiT,
                                                   u16* __restrict__ WoT,
                                                   int e0, int ne) {
  __shared__ __align__(16) u16 t2[64 * 66];   // [col][row-pair packed], stride 66
  int z = blockIdx.z;
  const float* src; u16* dst; int R, Cin, tr, tc;
  if (z < ne) { src = Wi + (size_t)(e0 + z) * D_ * FF_; dst = WiT + (size_t)z * FF_ * D_;
                R = D_; Cin = FF_; tr = blockIdx.y; tc = blockIdx.x; }
  else        { int q = z - ne;
                src = Wo + (size_t)(e0 + q) * FF_ * D_; dst = WoT + (size_t)q * D_ * FF_;
                R = FF_; Cin = D_; tr = blockIdx.x; tc = blockIdx.y; }
  int r0 = tr * 64, c0 = tc * 64;
  int tid = threadIdx.x;
  int irow = (tid >> 3) * 2, iseg = tid & 7;
  const float* s0 = src + (size_t)(r0 + irow) * Cin + c0 + iseg * 8;
  const float* s1 = s0 + Cin;
  float4 a0 = *(const float4*)(s0);
  float4 a1 = *(const float4*)(s0 + 4);
  float4 b0 = *(const float4*)(s1);
  float4 b1 = *(const float4*)(s1 + 4);
  float r0v[8] = {a0.x, a0.y, a0.z, a0.w, a1.x, a1.y, a1.z, a1.w};
  float r1v[8] = {b0.x, b0.y, b0.z, b0.w, b1.x, b1.y, b1.z, b1.w};
#pragma unroll
  for (int i = 0; i < 8; i++) {
    uint32_t u = (uint32_t)f2bf(r0v[i]) | ((uint32_t)f2bf(r1v[i]) << 16);
    *(uint32_t*)&t2[(iseg * 8 + i) * 66 + irow] = u;
  }
  __syncthreads();
#pragma unroll
  for (int j = 0; j < 2; j++) {
    int chunk = tid + 256 * j;
    int orow = chunk >> 3, oseg = chunk & 7;
    const u16* tp = &t2[orow * 66 + oseg * 8];
    uint4 o;
    o.x = *(const uint32_t*)(tp + 0);
    o.y = *(const uint32_t*)(tp + 2);
    o.z = *(const uint32_t*)(tp + 4);
    o.w = *(const uint32_t*)(tp + 6);
    *(uint4*)(dst + (size_t)(c0 + orow) * R + r0 + oseg * 8) = o;
  }
}

// ---------------- router: fp64 logits, softmax-max, argmax (one wave/token)
__global__ __launch_bounds__(256) void k_router(const float* __restrict__ x,
                                                const float* __restrict__ Wr,
                                                float* __restrict__ logits_out,
                                                float* __restrict__ prob_max,
                                                int* __restrict__ expert_idx) {
  int tid = threadIdx.x, wid = tid >> 6, lane = tid & 63;
  int t = blockIdx.x * 4 + wid;
  double lacc[8];
#pragma unroll
  for (int e = 0; e < 8; e++) lacc[e] = 0.0;
  const float* xr = x + (size_t)t * D_;
#pragma unroll
  for (int it = 0; it < 3; it++) {
    int d0 = (it * 64 + lane) * 4;
    float4 xv = *(const float4*)(xr + d0);
    float xs[4] = {xv.x, xv.y, xv.z, xv.w};
#pragma unroll
    for (int dd = 0; dd < 4; dd++) {
      double xd = (double)xs[dd];
      const float* wp = Wr + (size_t)(d0 + dd) * E_;
      float4 w0 = *(const float4*)(wp);
      float4 w1 = *(const float4*)(wp + 4);
      float ws[8] = {w0.x, w0.y, w0.z, w0.w, w1.x, w1.y, w1.z, w1.w};
#pragma unroll
      for (int e = 0; e < 8; e++) lacc[e] += xd * (double)ws[e];
    }
  }
#pragma unroll
  for (int m = 1; m < 64; m <<= 1) {
#pragma unroll
    for (int e = 0; e < 8; e++) lacc[e] += __shfl_xor(lacc[e], m, 64);
  }
  if (lane == 0) {
    double best = lacc[0]; int bi = 0;
#pragma unroll
    for (int e = 1; e < 8; e++) if (lacc[e] > best) { best = lacc[e]; bi = e; }
    double se = 0.0;
#pragma unroll
    for (int e = 0; e < 8; e++) se += exp(lacc[e] - best);
    prob_max[t] = (float)(1.0 / se);
    expert_idx[t] = bi;
    float* lo = logits_out + (size_t)t * E_;
    float4 o0, o1;
    o0.x = (float)lacc[0]; o0.y = (float)lacc[1]; o0.z = (float)lacc[2]; o0.w = (float)lacc[3];
    o1.x = (float)lacc[4]; o1.y = (float)lacc[5]; o1.z = (float)lacc[6]; o1.w = (float)lacc[7];
    *(float4*)(lo) = o0;
    *(float4*)(lo + 4) = o1;
  }
}

// ---------------- capacity scan per (b,e): HF cumsum capacity semantics
__global__ __launch_bounds__(256) void k_scan(const int* __restrict__ expert_idx,
                                              int* __restrict__ slot_token,
                                              int* __restrict__ cnt,
                                              float* __restrict__ idx_out) {
  int bid = blockIdx.x;                 // b*8+e
  int b = bid >> 3, e = bid & 7;
  int tid = threadIdx.x, wid = tid >> 6, lane = tid & 63;
  int s0 = tid * 8;
  int match[8]; int cl = 0;
#pragma unroll
  for (int j = 0; j < 8; j++) {
    match[j] = (expert_idx[b * S_ + s0 + j] == e);
    cl += match[j];
  }
  int inc = cl;
#pragma unroll
  for (int d = 1; d < 64; d <<= 1) {
    int v = __shfl_up(inc, (unsigned)d, 64);
    if (lane >= d) inc += v;
  }
  __shared__ int wt[4];
  if (lane == 63) wt[wid] = inc;
  __syncthreads();
  int base = 0;
#pragma unroll
  for (int w = 0; w < 4; w++) if (w < wid) base += wt[w];
  int total = wt[0] + wt[1] + wt[2] + wt[3];
  int pos = base + inc - cl;
#pragma unroll
  for (int j = 0; j < 8; j++) {
    if (match[j]) {
      bool keep = pos < C_;
      if (keep) slot_token[bid * C_ + pos] = s0 + j;
      idx_out[b * S_ + s0 + j] = keep ? (float)e : 0.0f;
      pos++;
    }
  }
  if (tid == 0) cnt[bid] = total < C_ ? total : C_;
}

// ---------------- out = prob_max * x (fp32) for ALL tokens; also emit xb = bf16(x)
__global__ __launch_bounds__(256) void k_init_out(const float* __restrict__ x,
                                                  const float* __restrict__ prob_max,
                                                  float* __restrict__ out,
                                                  u16* __restrict__ xb) {
  int g = blockIdx.x * 256 + threadIdx.x;       // 16384 tokens * 96 segs of 8
  int t = g / 96, seg = g % 96;
  float p = prob_max[t];
  const float* xr = x + (size_t)t * D_ + seg * 8;
  float4 v0 = *(const float4*)(xr);
  float4 v1 = *(const float4*)(xr + 4);
  float xs[8] = {v0.x, v0.y, v0.z, v0.w, v1.x, v1.y, v1.z, v1.w};
  float* orow = out + (size_t)t * D_ + seg * 8;
  float4 o0, o1;
  o0.x = p * xs[0]; o0.y = p * xs[1]; o0.z = p * xs[2]; o0.w = p * xs[3];
  o1.x = p * xs[4]; o1.y = p * xs[5]; o1.z = p * xs[6]; o1.w = p * xs[7];
  *(float4*)(orow) = o0;
  *(float4*)(orow + 4) = o1;
  uint4 xw;
  xw.x = (uint32_t)f2bf(xs[0]) | ((uint32_t)f2bf(xs[1]) << 16);
  xw.y = (uint32_t)f2bf(xs[2]) | ((uint32_t)f2bf(xs[3]) << 16);
  xw.z = (uint32_t)f2bf(xs[4]) | ((uint32_t)f2bf(xs[5]) << 16);
  xw.w = (uint32_t)f2bf(xs[6]) | ((uint32_t)f2bf(xs[7]) << 16);
  *(uint4*)(xb + (size_t)t * D_ + seg * 8) = xw;
}

// ---------------- GEMM1: h(bf16) = relu(Xb_gathered * WiT^T)
// 128x128xBK64 tile, 4 waves, global_load_lds staging, XOR LDS swizzle,
// 1D grid + XCD swizzle (n fastest -> m -> z).
__global__ __launch_bounds__(256) void k_gemm1(const u16* __restrict__ xb,
                                               const u16* __restrict__ WiT,
                                               u16* __restrict__ h,
                                               const int* __restrict__ slot_token,
                                               const int* __restrict__ cnt,
                                               int b0, int nb, int e0, int ne) {
  __shared__ __align__(16) u16 lA[128 * 64];
  __shared__ __align__(16) u16 lB[128 * 64];
  int f2 = xcd_swz(blockIdx.x, gridDim.x);
  int n_t = f2 % 24; int rest = f2 / 24;
  int m_t = rest % 3; int z = rest / 3;
  int el = z / nb, bl = z % nb;
  int e = e0 + el, b = b0 + bl;
  int be = b * 8 + e;
  int m_cnt = cnt[be];
  int m0 = m_t * 128;
  if (m0 >= m_cnt) return;               // m_cnt >= 1 past this point
  int n0 = n_t * 128;
  int tid = threadIdx.x, wid = tid >> 6, lane = tid & 63;
  // staging mapping: wave covers 8 rows x 64 cols per pass; 4 passes of 32 rows
  int r8 = lane >> 3;                    // 0..7
  int segb = (lane & 7) * 16;            // byte col within 128B row
  int xw = (r8 & 3) << 5;                // staging XOR (row&3 of every pass row)
  int gcol = (segb ^ xw) >> 1;           // u16 col to FETCH for linear LDS slot
  const u16* wbase = WiT + (size_t)el * FF_ * D_;
  const u16* gA[4]; const u16* gB[4];
#pragma unroll
  for (int p = 0; p < 4; p++) {
    int row = p * 32 + wid * 8 + r8;
    int ia = m0 + row; if (ia >= m_cnt) ia = m_cnt - 1;
    int t = slot_token[be * C_ + ia] & (S_ - 1);
    gA[p] = xb + (size_t)(b * S_ + t) * D_ + gcol;
    gB[p] = wbase + (size_t)(n0 + row) * D_ + gcol;
  }
  u16* sA = lA + (wid * 8 + r8) * 64 + (segb >> 1);   // byte = wid*1024 + lane*16
  u16* sB = lB + (wid * 8 + r8) * 64 + (segb >> 1);
  v4f acc[4][4];
#pragma unroll
  for (int mi = 0; mi < 4; mi++)
#pragma unroll
    for (int ni = 0; ni < 4; ni++) acc[mi][ni] = (v4f){0.f, 0.f, 0.f, 0.f};
  int wm = wid >> 1, wn = wid & 1;
  int lr = lane & 15, q = lane >> 4;
  int xr = (lr & 3) << 5;                // read XOR
  int kx0 = ((q * 16) ^ xr) >> 1;        // u16 offsets within row
  int kx1 = ((q * 16 + 64) ^ xr) >> 1;
  const u16* pa = lA + (wm * 64 + lr) * 64;
  const u16* pb = lB + (wn * 64 + lr) * 64;
  for (int k0 = 0; k0 < D_; k0 += 64) {
    __syncthreads();
#pragma unroll
    for (int p = 0; p < 4; p++) {
      gl_lds16(gA[p], sA + p * 2048);
      gl_lds16(gB[p], sB + p * 2048);
      gA[p] += 64; gB[p] += 64;
    }
    __syncthreads();
#pragma unroll
    for (int half = 0; half < 2; half++) {
      int kx = half ? kx1 : kx0;
      bf8v af[4], bf[4];
#pragma unroll
      for (int i = 0; i < 4; i++) af[i] = *(const bf8v*)(pa + i * 1024 + kx);
#pragma unroll
      for (int i = 0; i < 4; i++) bf[i] = *(const bf8v*)(pb + i * 1024 + kx);
#pragma unroll
      for (int mi = 0; mi < 4; mi++)
#pragma unroll
        for (int ni = 0; ni < 4; ni++)
          acc[mi][ni] = __builtin_amdgcn_mfma_f32_16x16x32_bf16(af[mi], bf[ni], acc[mi][ni], 0, 0, 0);
    }
  }
  size_t hb = (size_t)(el * nb + bl) * C_ * FF_;
#pragma unroll
  for (int mi = 0; mi < 4; mi++) {
#pragma unroll
    for (int r = 0; r < 4; r++) {
      int row = m0 + wm * 64 + mi * 16 + q * 4 + r;
      u16* hr = h + hb + (size_t)row * FF_ + n0 + wn * 64 + lr;
#pragma unroll
      for (int ni = 0; ni < 4; ni++) {
        float v = acc[mi][ni][r];
        hr[ni * 16] = f2bf(v > 0.f ? v : 0.f);
      }
    }
  }
}

// ---------------- GEMM2: scatter fp32 rows p * (h * WoT^T) into out
__global__ __launch_bounds__(256) void k_gemm2(const u16* __restrict__ h,
                                               const u16* __restrict__ WoT,
                                               float* __restrict__ out,
                                               const int* __restrict__ slot_token,
                                               const int* __restrict__ cnt,
                                               const float* __restrict__ prob_max,
                                               int b0, int nb, int e0, int ne) {
  __shared__ __align__(16) u16 lA[128 * 64];
  __shared__ __align__(16) u16 lB[128 * 64];
  int f2 = xcd_swz(blockIdx.x, gridDim.x);
  int n_t = f2 % 6; int rest = f2 / 6;
  int m_t = rest % 3; int z = rest / 3;
  int el = z / nb, bl = z % nb;
  int e = e0 + el, b = b0 + bl;
  int be = b * 8 + e;
  int m_cnt = cnt[be];
  int m0 = m_t * 128;
  if (m0 >= m_cnt) return;
  int n0 = n_t * 128;
  int tid = threadIdx.x, wid = tid >> 6, lane = tid & 63;
  int r8 = lane >> 3;
  int segb = (lane & 7) * 16;
  int xw = (r8 & 3) << 5;
  int gcol = (segb ^ xw) >> 1;
  size_t hb = (size_t)(el * nb + bl) * C_ * FF_;
  const u16* wbase = WoT + (size_t)el * D_ * FF_;
  const u16* gA[4]; const u16* gB[4];
#pragma unroll
  for (int p = 0; p < 4; p++) {
    int row = p * 32 + wid * 8 + r8;
    int ia = m0 + row; if (ia >= m_cnt) ia = m_cnt - 1;
    gA[p] = h + hb + (size_t)ia * FF_ + gcol;
    gB[p] = wbase + (size_t)(n0 + row) * FF_ + gcol;
  }
  u16* sA = lA + (wid * 8 + r8) * 64 + (segb >> 1);
  u16* sB = lB + (wid * 8 + r8) * 64 + (segb >> 1);
  v4f acc[4][4];
#pragma unroll
  for (int mi = 0; mi < 4; mi++)
#pragma unroll
    for (int ni = 0; ni < 4; ni++) acc[mi][ni] = (v4f){0.f, 0.f, 0.f, 0.f};
  int wm = wid >> 1, wn = wid & 1;
  int lr = lane & 15, q = lane >> 4;
  int xr = (lr & 3) << 5;
  int kx0 = ((q * 16) ^ xr) >> 1;
  int kx1 = ((q * 16 + 64) ^ xr) >> 1;
  const u16* pa = lA + (wm * 64 + lr) * 64;
  const u16* pb = lB + (wn * 64 + lr) * 64;
  for (int k0 = 0; k0 < FF_; k0 += 64) {
    __syncthreads();
#pragma unroll
    for (int p = 0; p < 4; p++) {
      gl_lds16(gA[p], sA + p * 2048);
      gl_lds16(gB[p], sB + p * 2048);
      gA[p] += 64; gB[p] += 64;
    }
    __syncthreads();
#pragma unroll
    for (int half = 0; half < 2; half++) {
      int kx = half ? kx1 : kx0;
      bf8v af[4], bf[4];
#pragma unroll
      for (int i = 0; i < 4; i++) af[i] = *(const bf8v*)(pa + i * 1024 + kx);
#pragma unroll
      for (int i = 0; i < 4; i++) bf[i] = *(const bf8v*)(pb + i * 1024 + kx);
#pragma unroll
      for (int mi = 0; mi < 4; mi++)
#pragma unroll
        for (int ni = 0; ni < 4; ni++)
          acc[mi][ni] = __builtin_amdgcn_mfma_f32_16x16x32_bf16(af[mi], bf[ni], acc[mi][ni], 0, 0, 0);
    }
  }
#pragma unroll
  for (int mi = 0; mi < 4; mi++) {
#pragma unroll
    for (int r = 0; r < 4; r++) {
      int row = m0 + wm * 64 + mi * 16 + q * 4 + r;
      if (row < m_cnt) {
        int tok = slot_token[be * C_ + row] & (S_ - 1);
        float p = prob_max[b * S_ + tok];
        float* orow = out + (size_t)(b * S_ + tok) * D_ + n0 + wn * 64 + lr;
#pragma unroll
        for (int ni = 0; ni < 4; ni++)
          orow[ni * 16] = acc[mi][ni][r] * p;
      }
    }
  }
}

extern "C" void kernel_launch(void* const* d_in, const int* in_sizes, int n_in,
                              void* d_out, int out_size, void* d_ws, size_t ws_size,
                              hipStream_t stream) {
  const float* x  = (const float*)d_in[0];
  const float* Wr = (const float*)d_in[1];
  const float* Wi = (const float*)d_in[2];
  const float* Wo = (const float*)d_in[3];
  float* out = (float*)d_out;
  float* logits_out = out + (size_t)B_ * S_ * D_;
  float* idx_out = logits_out + (size_t)B_ * S_ * E_;

  char* ws = (char*)d_ws;
  float* prob_max   = (float*)(ws);             // 65,536 B
  int*   expert_idx = (int*)(ws + 65536);       // 65,536 B
  int*   slot_token = (int*)(ws + 131072);      // 98,304 B
  int*   cnt        = (int*)(ws + 229376);      // 256 B
  u16*   xb         = (u16*)(ws + 229632);      // 25,165,824 B (bf16 copy of x)
  const size_t chunk0 = 25395456ull;

  const int cand_ne[7] = {8, 4, 2, 1, 1, 1, 1};
  const int cand_nb[7] = {8, 8, 8, 8, 4, 2, 1};
  int ne = 1, nb = 1;
  for (int i = 0; i < 7; i++) {
    size_t need = chunk0 + (size_t)cand_ne[i] * 9437184ull
                + (size_t)cand_ne[i] * cand_nb[i] * 2359296ull;
    if (need <= ws_size) { ne = cand_ne[i]; nb = cand_nb[i]; break; }
  }
  u16* WiT = (u16*)(ws + chunk0);               // ne * 4,718,592 B
  u16* WoT = WiT + (size_t)ne * FF_ * D_;       // ne * 4,718,592 B
  u16* h   = WoT + (size_t)ne * D_ * FF_;       // ne * nb * 2,359,296 B

  k_router<<<dim3(4096), 256, 0, stream>>>(x, Wr, logits_out, prob_max, expert_idx);
  k_scan<<<dim3(64), 256, 0, stream>>>(expert_idx, slot_token, cnt, idx_out);
  k_init_out<<<dim3(6144), 256, 0, stream>>>(x, prob_max, out, xb);
  for (int e0 = 0; e0 < E_; e0 += ne) {
    k_transpose<<<dim3(48, 12, 2 * ne), 256, 0, stream>>>(Wi, Wo, WiT, WoT, e0, ne);
    for (int b0 = 0; b0 < B_; b0 += nb) {
      int zc = nb * ne;
      k_gemm1<<<dim3(24 * 3 * zc), 256, 0, stream>>>(xb, WiT, h, slot_token, cnt, b0, nb, e0, ne);
      k_gemm2<<<dim3(6 * 3 * zc), 256, 0, stream>>>(h, WoT, out, slot_token, cnt, prob_max, b0, nb, e0, ne);
    }
  }
}

// Round 3
// 602.083 us; speedup vs baseline: 1.0476x; 1.0476x over previous
//
#include <hip/hip_runtime.h>
#include <stdint.h>

#define B_ 8
#define S_ 2048
#define D_ 768
#define FF_ 3072
#define E_ 8
#define C_ 384

typedef unsigned short u16;
typedef float  v4f  __attribute__((ext_vector_type(4)));
typedef __bf16 bf8v __attribute__((ext_vector_type(8)));

__device__ __forceinline__ u16 f2bf(float f) {
  union { float f; uint32_t i; } v; v.f = f;
  uint32_t u = v.i;
  return (u16)((u + 0x7FFFu + ((u >> 16) & 1u)) >> 16);   // RNE
}

// async global->LDS, 16B per lane. LDS dest must be wave-uniform base + lane*16.
typedef const __attribute__((address_space(1))) void* gas1_t;
typedef __attribute__((address_space(3))) void* las3_t;
__device__ __forceinline__ void gl_lds16(const void* g, void* l) {
  __builtin_amdgcn_global_load_lds((gas1_t)g, (las3_t)l, 16, 0, 0);
}

// ---------------- weight transpose+convert for expert chunk [e0, e0+ne)
__global__ __launch_bounds__(256) void k_transpose(const float* __restrict__ Wi,
                                                   const float* __restrict__ Wo,
                                                   u16* __restrict__ WiT,
                                                   u16* __restrict__ WoT,
                                                   int e0, int ne) {
  __shared__ __align__(16) u16 t2[64 * 66];   // [col][row-pair packed], stride 66
  int z = blockIdx.z;
  const float* src; u16* dst; int R, Cin, tr, tc;
  if (z < ne) { src = Wi + (size_t)(e0 + z) * D_ * FF_; dst = WiT + (size_t)z * FF_ * D_;
                R = D_; Cin = FF_; tr = blockIdx.y; tc = blockIdx.x; }
  else        { int q = z - ne;
                src = Wo + (size_t)(e0 + q) * FF_ * D_; dst = WoT + (size_t)q * D_ * FF_;
                R = FF_; Cin = D_; tr = blockIdx.x; tc = blockIdx.y; }
  int r0 = tr * 64, c0 = tc * 64;
  int tid = threadIdx.x;
  int irow = (tid >> 3) * 2, iseg = tid & 7;
  const float* s0 = src + (size_t)(r0 + irow) * Cin + c0 + iseg * 8;
  const float* s1 = s0 + Cin;
  float4 a0 = *(const float4*)(s0);
  float4 a1 = *(const float4*)(s0 + 4);
  float4 b0 = *(const float4*)(s1);
  float4 b1 = *(const float4*)(s1 + 4);
  float r0v[8] = {a0.x, a0.y, a0.z, a0.w, a1.x, a1.y, a1.z, a1.w};
  float r1v[8] = {b0.x, b0.y, b0.z, b0.w, b1.x, b1.y, b1.z, b1.w};
#pragma unroll
  for (int i = 0; i < 8; i++) {
    uint32_t u = (uint32_t)f2bf(r0v[i]) | ((uint32_t)f2bf(r1v[i]) << 16);
    *(uint32_t*)&t2[(iseg * 8 + i) * 66 + irow] = u;
  }
  __syncthreads();
#pragma unroll
  for (int j = 0; j < 2; j++) {
    int chunk = tid + 256 * j;
    int orow = chunk >> 3, oseg = chunk & 7;
    const u16* tp = &t2[orow * 66 + oseg * 8];
    uint4 o;
    o.x = *(const uint32_t*)(tp + 0);
    o.y = *(const uint32_t*)(tp + 2);
    o.z = *(const uint32_t*)(tp + 4);
    o.w = *(const uint32_t*)(tp + 6);
    *(uint4*)(dst + (size_t)(c0 + orow) * R + r0 + oseg * 8) = o;
  }
}

// ---------------- router: fp64 logits, softmax-max, argmax (one wave/token)
__global__ __launch_bounds__(256) void k_router(const float* __restrict__ x,
                                                const float* __restrict__ Wr,
                                                float* __restrict__ logits_out,
                                                float* __restrict__ prob_max,
                                                int* __restrict__ expert_idx) {
  int tid = threadIdx.x, wid = tid >> 6, lane = tid & 63;
  int t = blockIdx.x * 4 + wid;
  double lacc[8];
#pragma unroll
  for (int e = 0; e < 8; e++) lacc[e] = 0.0;
  const float* xr = x + (size_t)t * D_;
#pragma unroll
  for (int it = 0; it < 3; it++) {
    int d0 = (it * 64 + lane) * 4;
    float4 xv = *(const float4*)(xr + d0);
    float xs[4] = {xv.x, xv.y, xv.z, xv.w};
#pragma unroll
    for (int dd = 0; dd < 4; dd++) {
      double xd = (double)xs[dd];
      const float* wp = Wr + (size_t)(d0 + dd) * E_;
      float4 w0 = *(const float4*)(wp);
      float4 w1 = *(const float4*)(wp + 4);
      float ws[8] = {w0.x, w0.y, w0.z, w0.w, w1.x, w1.y, w1.z, w1.w};
#pragma unroll
      for (int e = 0; e < 8; e++) lacc[e] += xd * (double)ws[e];
    }
  }
#pragma unroll
  for (int m = 1; m < 64; m <<= 1) {
#pragma unroll
    for (int e = 0; e < 8; e++) lacc[e] += __shfl_xor(lacc[e], m, 64);
  }
  if (lane == 0) {
    double best = lacc[0]; int bi = 0;
#pragma unroll
    for (int e = 1; e < 8; e++) if (lacc[e] > best) { best = lacc[e]; bi = e; }
    double se = 0.0;
#pragma unroll
    for (int e = 0; e < 8; e++) se += exp(lacc[e] - best);
    prob_max[t] = (float)(1.0 / se);
    expert_idx[t] = bi;
    float* lo = logits_out + (size_t)t * E_;
    float4 o0, o1;
    o0.x = (float)lacc[0]; o0.y = (float)lacc[1]; o0.z = (float)lacc[2]; o0.w = (float)lacc[3];
    o1.x = (float)lacc[4]; o1.y = (float)lacc[5]; o1.z = (float)lacc[6]; o1.w = (float)lacc[7];
    *(float4*)(lo) = o0;
    *(float4*)(lo + 4) = o1;
  }
}

// ---------------- capacity scan per (b,e): HF cumsum capacity semantics
__global__ __launch_bounds__(256) void k_scan(const int* __restrict__ expert_idx,
                                              int* __restrict__ slot_token,
                                              int* __restrict__ cnt,
                                              float* __restrict__ idx_out) {
  int bid = blockIdx.x;                 // b*8+e
  int b = bid >> 3, e = bid & 7;
  int tid = threadIdx.x, wid = tid >> 6, lane = tid & 63;
  int s0 = tid * 8;
  int match[8]; int cl = 0;
#pragma unroll
  for (int j = 0; j < 8; j++) {
    match[j] = (expert_idx[b * S_ + s0 + j] == e);
    cl += match[j];
  }
  int inc = cl;
#pragma unroll
  for (int d = 1; d < 64; d <<= 1) {
    int v = __shfl_up(inc, (unsigned)d, 64);
    if (lane >= d) inc += v;
  }
  __shared__ int wt[4];
  if (lane == 63) wt[wid] = inc;
  __syncthreads();
  int base = 0;
#pragma unroll
  for (int w = 0; w < 4; w++) if (w < wid) base += wt[w];
  int total = wt[0] + wt[1] + wt[2] + wt[3];
  int pos = base + inc - cl;
#pragma unroll
  for (int j = 0; j < 8; j++) {
    if (match[j]) {
      bool keep = pos < C_;
      if (keep) slot_token[bid * C_ + pos] = s0 + j;
      idx_out[b * S_ + s0 + j] = keep ? (float)e : 0.0f;
      pos++;
    }
  }
  if (tid == 0) cnt[bid] = total < C_ ? total : C_;
}

// ---------------- out = prob_max * x (fp32) for ALL tokens; also emit xb = bf16(x)
__global__ __launch_bounds__(256) void k_init_out(const float* __restrict__ x,
                                                  const float* __restrict__ prob_max,
                                                  float* __restrict__ out,
                                                  u16* __restrict__ xb) {
  int g = blockIdx.x * 256 + threadIdx.x;       // 16384 tokens * 96 segs of 8
  int t = g / 96, seg = g % 96;
  float p = prob_max[t];
  const float* xr = x + (size_t)t * D_ + seg * 8;
  float4 v0 = *(const float4*)(xr);
  float4 v1 = *(const float4*)(xr + 4);
  float xs[8] = {v0.x, v0.y, v0.z, v0.w, v1.x, v1.y, v1.z, v1.w};
  float* orow = out + (size_t)t * D_ + seg * 8;
  float4 o0, o1;
  o0.x = p * xs[0]; o0.y = p * xs[1]; o0.z = p * xs[2]; o0.w = p * xs[3];
  o1.x = p * xs[4]; o1.y = p * xs[5]; o1.z = p * xs[6]; o1.w = p * xs[7];
  *(float4*)(orow) = o0;
  *(float4*)(orow + 4) = o1;
  uint4 xw;
  xw.x = (uint32_t)f2bf(xs[0]) | ((uint32_t)f2bf(xs[1]) << 16);
  xw.y = (uint32_t)f2bf(xs[2]) | ((uint32_t)f2bf(xs[3]) << 16);
  xw.z = (uint32_t)f2bf(xs[4]) | ((uint32_t)f2bf(xs[5]) << 16);
  xw.w = (uint32_t)f2bf(xs[6]) | ((uint32_t)f2bf(xs[7]) << 16);
  *(uint4*)(xb + (size_t)t * D_ + seg * 8) = xw;
}

// ---------------- GEMM1: h(bf16) = relu(Xb_gathered * WiT^T)
// 128x128x32 tile, 4 waves, global_load_lds, DOUBLE-BUFFERED 2-phase pipeline:
// stage(next) -> compute(cur) -> one barrier (vmcnt drain) per K-step.
__global__ __launch_bounds__(256) void k_gemm1(const u16* __restrict__ xb,
                                               const u16* __restrict__ WiT,
                                               u16* __restrict__ h,
                                               const int* __restrict__ slot_token,
                                               const int* __restrict__ cnt,
                                               int b0, int nb, int e0, int ne) {
  __shared__ __align__(16) u16 lA[2 * 128 * 32];   // 2 x 8KB
  __shared__ __align__(16) u16 lB[2 * 128 * 32];
  int z = blockIdx.z;
  int el = z / nb, bl = z % nb;
  int e = e0 + el, b = b0 + bl;
  int be = b * 8 + e;
  int m_cnt = cnt[be];
  int m0 = blockIdx.y * 128;
  if (m0 >= m_cnt) return;
  int n0 = blockIdx.x * 128;
  int tid = threadIdx.x, wid = tid >> 6, lane = tid & 63;
  int srow = wid * 16 + (lane >> 2);    // 0..63
  int kseg = (lane & 3) * 8;
  int ia0 = m0 + srow;        if (ia0 >= m_cnt) ia0 = m_cnt - 1;
  int ia1 = m0 + srow + 64;   if (ia1 >= m_cnt) ia1 = m_cnt - 1;
  int t0 = slot_token[be * C_ + ia0] & (S_ - 1);
  int t1 = slot_token[be * C_ + ia1] & (S_ - 1);
  const u16* gA0 = xb + (size_t)(b * S_ + t0) * D_ + kseg;
  const u16* gA1 = xb + (size_t)(b * S_ + t1) * D_ + kseg;
  const u16* wbase = WiT + (size_t)el * FF_ * D_;
  const u16* gB0 = wbase + (size_t)(n0 + srow) * D_ + kseg;
  const u16* gB1 = wbase + (size_t)(n0 + srow + 64) * D_ + kseg;
  // LDS dests (buffer 0): byte offset = 1024*wid + 16*lane per half -> linear
  u16* sA0 = lA + srow * 32 + kseg;
  u16* sA1 = lA + (64 + srow) * 32 + kseg;
  u16* sB0 = lB + srow * 32 + kseg;
  u16* sB1 = lB + (64 + srow) * 32 + kseg;
  v4f acc[4][4];
#pragma unroll
  for (int mi = 0; mi < 4; mi++)
#pragma unroll
    for (int ni = 0; ni < 4; ni++) acc[mi][ni] = (v4f){0.f, 0.f, 0.f, 0.f};
  int wm = wid >> 1, wn = wid & 1;
  int lr = lane & 15, q = lane >> 4;
  const u16* pa = lA + (wm * 64 + lr) * 32 + q * 8;
  const u16* pb = lB + (wn * 64 + lr) * 32 + q * 8;
  // prologue: stage K-tile 0 into buffer 0
  gl_lds16(gA0, sA0); gl_lds16(gA1, sA1);
  gl_lds16(gB0, sB0); gl_lds16(gB1, sB1);
  gA0 += 32; gA1 += 32; gB0 += 32; gB1 += 32;
  __syncthreads();
  int cur = 0;
  for (int k0 = 0; k0 < D_; k0 += 32) {
    if (k0 + 32 < D_) {                 // stage NEXT tile into other buffer
      int nx = (cur ^ 1) * 4096;
      gl_lds16(gA0, sA0 + nx); gl_lds16(gA1, sA1 + nx);
      gl_lds16(gB0, sB0 + nx); gl_lds16(gB1, sB1 + nx);
      gA0 += 32; gA1 += 32; gB0 += 32; gB1 += 32;
    }
    int cb = cur * 4096;
    bf8v af[4], bf[4];
#pragma unroll
    for (int i = 0; i < 4; i++) af[i] = *(const bf8v*)(pa + cb + i * 512);
#pragma unroll
    for (int i = 0; i < 4; i++) bf[i] = *(const bf8v*)(pb + cb + i * 512);
#pragma unroll
    for (int mi = 0; mi < 4; mi++)
#pragma unroll
      for (int ni = 0; ni < 4; ni++)
        acc[mi][ni] = __builtin_amdgcn_mfma_f32_16x16x32_bf16(af[mi], bf[ni], acc[mi][ni], 0, 0, 0);
    __syncthreads();                    // drains vmcnt (next tile ready) + reads done
    cur ^= 1;
  }
  size_t hb = (size_t)(el * nb + bl) * C_ * FF_;
#pragma unroll
  for (int mi = 0; mi < 4; mi++) {
#pragma unroll
    for (int r = 0; r < 4; r++) {
      int row = m0 + wm * 64 + mi * 16 + q * 4 + r;
      u16* hr = h + hb + (size_t)row * FF_ + n0 + wn * 64 + lr;
#pragma unroll
      for (int ni = 0; ni < 4; ni++) {
        float v = acc[mi][ni][r];
        hr[ni * 16] = f2bf(v > 0.f ? v : 0.f);
      }
    }
  }
}

// ---------------- GEMM2: scatter fp32 rows p * (h * WoT^T) into out
__global__ __launch_bounds__(256) void k_gemm2(const u16* __restrict__ h,
                                               const u16* __restrict__ WoT,
                                               float* __restrict__ out,
                                               const int* __restrict__ slot_token,
                                               const int* __restrict__ cnt,
                                               const float* __restrict__ prob_max,
                                               int b0, int nb, int e0, int ne) {
  __shared__ __align__(16) u16 lA[2 * 128 * 32];
  __shared__ __align__(16) u16 lB[2 * 128 * 32];
  int z = blockIdx.z;
  int el = z / nb, bl = z % nb;
  int e = e0 + el, b = b0 + bl;
  int be = b * 8 + e;
  int m_cnt = cnt[be];
  int m0 = blockIdx.y * 128;
  if (m0 >= m_cnt) return;
  int n0 = blockIdx.x * 128;
  int tid = threadIdx.x, wid = tid >> 6, lane = tid & 63;
  int srow = wid * 16 + (lane >> 2);
  int kseg = (lane & 3) * 8;
  size_t hb = (size_t)(el * nb + bl) * C_ * FF_;
  int ia0 = m0 + srow;        if (ia0 >= m_cnt) ia0 = m_cnt - 1;
  int ia1 = m0 + srow + 64;   if (ia1 >= m_cnt) ia1 = m_cnt - 1;
  const u16* gA0 = h + hb + (size_t)ia0 * FF_ + kseg;
  const u16* gA1 = h + hb + (size_t)ia1 * FF_ + kseg;
  const u16* wbase = WoT + (size_t)el * D_ * FF_;
  const u16* gB0 = wbase + (size_t)(n0 + srow) * FF_ + kseg;
  const u16* gB1 = wbase + (size_t)(n0 + srow + 64) * FF_ + kseg;
  u16* sA0 = lA + srow * 32 + kseg;
  u16* sA1 = lA + (64 + srow) * 32 + kseg;
  u16* sB0 = lB + srow * 32 + kseg;
  u16* sB1 = lB + (64 + srow) * 32 + kseg;
  v4f acc[4][4];
#pragma unroll
  for (int mi = 0; mi < 4; mi++)
#pragma unroll
    for (int ni = 0; ni < 4; ni++) acc[mi][ni] = (v4f){0.f, 0.f, 0.f, 0.f};
  int wm = wid >> 1, wn = wid & 1;
  int lr = lane & 15, q = lane >> 4;
  const u16* pa = lA + (wm * 64 + lr) * 32 + q * 8;
  const u16* pb = lB + (wn * 64 + lr) * 32 + q * 8;
  gl_lds16(gA0, sA0); gl_lds16(gA1, sA1);
  gl_lds16(gB0, sB0); gl_lds16(gB1, sB1);
  gA0 += 32; gA1 += 32; gB0 += 32; gB1 += 32;
  __syncthreads();
  int cur = 0;
  for (int k0 = 0; k0 < FF_; k0 += 32) {
    if (k0 + 32 < FF_) {
      int nx = (cur ^ 1) * 4096;
      gl_lds16(gA0, sA0 + nx); gl_lds16(gA1, sA1 + nx);
      gl_lds16(gB0, sB0 + nx); gl_lds16(gB1, sB1 + nx);
      gA0 += 32; gA1 += 32; gB0 += 32; gB1 += 32;
    }
    int cb = cur * 4096;
    bf8v af[4], bf[4];
#pragma unroll
    for (int i = 0; i < 4; i++) af[i] = *(const bf8v*)(pa + cb + i * 512);
#pragma unroll
    for (int i = 0; i < 4; i++) bf[i] = *(const bf8v*)(pb + cb + i * 512);
#pragma unroll
    for (int mi = 0; mi < 4; mi++)
#pragma unroll
      for (int ni = 0; ni < 4; ni++)
        acc[mi][ni] = __builtin_amdgcn_mfma_f32_16x16x32_bf16(af[mi], bf[ni], acc[mi][ni], 0, 0, 0);
    __syncthreads();
    cur ^= 1;
  }
#pragma unroll
  for (int mi = 0; mi < 4; mi++) {
#pragma unroll
    for (int r = 0; r < 4; r++) {
      int row = m0 + wm * 64 + mi * 16 + q * 4 + r;
      if (row < m_cnt) {
        int tok = slot_token[be * C_ + row] & (S_ - 1);
        float p = prob_max[b * S_ + tok];
        float* orow = out + (size_t)(b * S_ + tok) * D_ + n0 + wn * 64 + lr;
#pragma unroll
        for (int ni = 0; ni < 4; ni++)
          orow[ni * 16] = acc[mi][ni][r] * p;
      }
    }
  }
}

extern "C" void kernel_launch(void* const* d_in, const int* in_sizes, int n_in,
                              void* d_out, int out_size, void* d_ws, size_t ws_size,
                              hipStream_t stream) {
  const float* x  = (const float*)d_in[0];
  const float* Wr = (const float*)d_in[1];
  const float* Wi = (const float*)d_in[2];
  const float* Wo = (const float*)d_in[3];
  float* out = (float*)d_out;
  float* logits_out = out + (size_t)B_ * S_ * D_;
  float* idx_out = logits_out + (size_t)B_ * S_ * E_;

  char* ws = (char*)d_ws;
  float* prob_max   = (float*)(ws);             // 65,536 B
  int*   expert_idx = (int*)(ws + 65536);       // 65,536 B
  int*   slot_token = (int*)(ws + 131072);      // 98,304 B
  int*   cnt        = (int*)(ws + 229376);      // 256 B
  u16*   xb         = (u16*)(ws + 229632);      // 25,165,824 B (bf16 copy of x)
  const size_t chunk0 = 25395456ull;

  const int cand_ne[7] = {8, 4, 2, 1, 1, 1, 1};
  const int cand_nb[7] = {8, 8, 8, 8, 4, 2, 1};
  int ne = 1, nb = 1;
  for (int i = 0; i < 7; i++) {
    size_t need = chunk0 + (size_t)cand_ne[i] * 9437184ull
                + (size_t)cand_ne[i] * cand_nb[i] * 2359296ull;
    if (need <= ws_size) { ne = cand_ne[i]; nb = cand_nb[i]; break; }
  }
  u16* WiT = (u16*)(ws + chunk0);               // ne * 4,718,592 B
  u16* WoT = WiT + (size_t)ne * FF_ * D_;       // ne * 4,718,592 B
  u16* h   = WoT + (size_t)ne * D_ * FF_;       // ne * nb * 2,359,296 B

  k_router<<<dim3(4096), 256, 0, stream>>>(x, Wr, logits_out, prob_max, expert_idx);
  k_scan<<<dim3(64), 256, 0, stream>>>(expert_idx, slot_token, cnt, idx_out);
  k_init_out<<<dim3(6144), 256, 0, stream>>>(x, prob_max, out, xb);
  for (int e0 = 0; e0 < E_; e0 += ne) {
    k_transpose<<<dim3(48, 12, 2 * ne), 256, 0, stream>>>(Wi, Wo, WiT, WoT, e0, ne);
    for (int b0 = 0; b0 < B_; b0 += nb) {
      k_gemm1<<<dim3(24, 3, nb * ne), 256, 0, stream>>>(xb, WiT, h, slot_token, cnt, b0, nb, e0, ne);
      k_gemm2<<<dim3(6, 3, nb * ne), 256, 0, stream>>>(h, WoT, out, slot_token, cnt, prob_max, b0, nb, e0, ne);
    }
  }
}

// Round 4
// 576.823 us; speedup vs baseline: 1.0935x; 1.0438x over previous
//
#include <hip/hip_runtime.h>
#include <stdint.h>

#define B_ 8
#define S_ 2048
#define D_ 768
#define FF_ 3072
#define E_ 8
#define C_ 384

typedef unsigned short u16;
typedef float  v4f  __attribute__((ext_vector_type(4)));
typedef __bf16 bf8v __attribute__((ext_vector_type(8)));

__device__ __forceinline__ u16 f2bf(float f) {
  union { float f; uint32_t i; } v; v.f = f;
  uint32_t u = v.i;
  return (u16)((u + 0x7FFFu + ((u >> 16) & 1u)) >> 16);   // RNE
}

// async global->LDS, 16B per lane. LDS dest must be wave-uniform base + lane*16.
typedef const __attribute__((address_space(1))) void* gas1_t;
typedef __attribute__((address_space(3))) void* las3_t;
__device__ __forceinline__ void gl_lds16(const void* g, void* l) {
  __builtin_amdgcn_global_load_lds((gas1_t)g, (las3_t)l, 16, 0, 0);
}

// ---------------- weight transpose+convert for expert chunk [e0, e0+ne)
__global__ __launch_bounds__(256) void k_transpose(const float* __restrict__ Wi,
                                                   const float* __restrict__ Wo,
                                                   u16* __restrict__ WiT,
                                                   u16* __restrict__ WoT,
                                                   int e0, int ne) {
  __shared__ __align__(16) u16 t2[64 * 66];   // [col][row-pair packed], stride 66
  int z = blockIdx.z;
  const float* src; u16* dst; int R, Cin, tr, tc;
  if (z < ne) { src = Wi + (size_t)(e0 + z) * D_ * FF_; dst = WiT + (size_t)z * FF_ * D_;
                R = D_; Cin = FF_; tr = blockIdx.y; tc = blockIdx.x; }
  else        { int q = z - ne;
                src = Wo + (size_t)(e0 + q) * FF_ * D_; dst = WoT + (size_t)q * D_ * FF_;
                R = FF_; Cin = D_; tr = blockIdx.x; tc = blockIdx.y; }
  int r0 = tr * 64, c0 = tc * 64;
  int tid = threadIdx.x;
  int irow = (tid >> 3) * 2, iseg = tid & 7;
  const float* s0 = src + (size_t)(r0 + irow) * Cin + c0 + iseg * 8;
  const float* s1 = s0 + Cin;
  float4 a0 = *(const float4*)(s0);
  float4 a1 = *(const float4*)(s0 + 4);
  float4 b0 = *(const float4*)(s1);
  float4 b1 = *(const float4*)(s1 + 4);
  float r0v[8] = {a0.x, a0.y, a0.z, a0.w, a1.x, a1.y, a1.z, a1.w};
  float r1v[8] = {b0.x, b0.y, b0.z, b0.w, b1.x, b1.y, b1.z, b1.w};
#pragma unroll
  for (int i = 0; i < 8; i++) {
    uint32_t u = (uint32_t)f2bf(r0v[i]) | ((uint32_t)f2bf(r1v[i]) << 16);
    *(uint32_t*)&t2[(iseg * 8 + i) * 66 + irow] = u;
  }
  __syncthreads();
#pragma unroll
  for (int j = 0; j < 2; j++) {
    int chunk = tid + 256 * j;
    int orow = chunk >> 3, oseg = chunk & 7;
    const u16* tp = &t2[orow * 66 + oseg * 8];
    uint4 o;
    o.x = *(const uint32_t*)(tp + 0);
    o.y = *(const uint32_t*)(tp + 2);
    o.z = *(const uint32_t*)(tp + 4);
    o.w = *(const uint32_t*)(tp + 6);
    *(uint4*)(dst + (size_t)(c0 + orow) * R + r0 + oseg * 8) = o;
  }
}

// ---------------- router: fp64 logits, softmax-max, argmax (one wave/token)
__global__ __launch_bounds__(256) void k_router(const float* __restrict__ x,
                                                const float* __restrict__ Wr,
                                                float* __restrict__ logits_out,
                                                float* __restrict__ prob_max,
                                                int* __restrict__ expert_idx) {
  int tid = threadIdx.x, wid = tid >> 6, lane = tid & 63;
  int t = blockIdx.x * 4 + wid;
  double lacc[8];
#pragma unroll
  for (int e = 0; e < 8; e++) lacc[e] = 0.0;
  const float* xr = x + (size_t)t * D_;
#pragma unroll
  for (int it = 0; it < 3; it++) {
    int d0 = (it * 64 + lane) * 4;
    float4 xv = *(const float4*)(xr + d0);
    float xs[4] = {xv.x, xv.y, xv.z, xv.w};
#pragma unroll
    for (int dd = 0; dd < 4; dd++) {
      double xd = (double)xs[dd];
      const float* wp = Wr + (size_t)(d0 + dd) * E_;
      float4 w0 = *(const float4*)(wp);
      float4 w1 = *(const float4*)(wp + 4);
      float ws[8] = {w0.x, w0.y, w0.z, w0.w, w1.x, w1.y, w1.z, w1.w};
#pragma unroll
      for (int e = 0; e < 8; e++) lacc[e] += xd * (double)ws[e];
    }
  }
#pragma unroll
  for (int m = 1; m < 64; m <<= 1) {
#pragma unroll
    for (int e = 0; e < 8; e++) lacc[e] += __shfl_xor(lacc[e], m, 64);
  }
  if (lane == 0) {
    double best = lacc[0]; int bi = 0;
#pragma unroll
    for (int e = 1; e < 8; e++) if (lacc[e] > best) { best = lacc[e]; bi = e; }
    double se = 0.0;
#pragma unroll
    for (int e = 0; e < 8; e++) se += exp(lacc[e] - best);
    prob_max[t] = (float)(1.0 / se);
    expert_idx[t] = bi;
    float* lo = logits_out + (size_t)t * E_;
    float4 o0, o1;
    o0.x = (float)lacc[0]; o0.y = (float)lacc[1]; o0.z = (float)lacc[2]; o0.w = (float)lacc[3];
    o1.x = (float)lacc[4]; o1.y = (float)lacc[5]; o1.z = (float)lacc[6]; o1.w = (float)lacc[7];
    *(float4*)(lo) = o0;
    *(float4*)(lo + 4) = o1;
  }
}

// ---------------- capacity scan per (b,e): HF cumsum capacity semantics
__global__ __launch_bounds__(256) void k_scan(const int* __restrict__ expert_idx,
                                              int* __restrict__ slot_token,
                                              int* __restrict__ cnt,
                                              float* __restrict__ idx_out) {
  int bid = blockIdx.x;                 // b*8+e
  int b = bid >> 3, e = bid & 7;
  int tid = threadIdx.x, wid = tid >> 6, lane = tid & 63;
  int s0 = tid * 8;
  int match[8]; int cl = 0;
#pragma unroll
  for (int j = 0; j < 8; j++) {
    match[j] = (expert_idx[b * S_ + s0 + j] == e);
    cl += match[j];
  }
  int inc = cl;
#pragma unroll
  for (int d = 1; d < 64; d <<= 1) {
    int v = __shfl_up(inc, (unsigned)d, 64);
    if (lane >= d) inc += v;
  }
  __shared__ int wt[4];
  if (lane == 63) wt[wid] = inc;
  __syncthreads();
  int base = 0;
#pragma unroll
  for (int w = 0; w < 4; w++) if (w < wid) base += wt[w];
  int total = wt[0] + wt[1] + wt[2] + wt[3];
  int pos = base + inc - cl;
#pragma unroll
  for (int j = 0; j < 8; j++) {
    if (match[j]) {
      bool keep = pos < C_;
      if (keep) slot_token[bid * C_ + pos] = s0 + j;
      idx_out[b * S_ + s0 + j] = keep ? (float)e : 0.0f;
      pos++;
    }
  }
  if (tid == 0) cnt[bid] = total < C_ ? total : C_;
}

// ---------------- out = prob_max * x (fp32) for ALL tokens; also emit xb = bf16(x)
__global__ __launch_bounds__(256) void k_init_out(const float* __restrict__ x,
                                                  const float* __restrict__ prob_max,
                                                  float* __restrict__ out,
                                                  u16* __restrict__ xb) {
  int g = blockIdx.x * 256 + threadIdx.x;       // 16384 tokens * 96 segs of 8
  int t = g / 96, seg = g % 96;
  float p = prob_max[t];
  const float* xr = x + (size_t)t * D_ + seg * 8;
  float4 v0 = *(const float4*)(xr);
  float4 v1 = *(const float4*)(xr + 4);
  float xs[8] = {v0.x, v0.y, v0.z, v0.w, v1.x, v1.y, v1.z, v1.w};
  float* orow = out + (size_t)t * D_ + seg * 8;
  float4 o0, o1;
  o0.x = p * xs[0]; o0.y = p * xs[1]; o0.z = p * xs[2]; o0.w = p * xs[3];
  o1.x = p * xs[4]; o1.y = p * xs[5]; o1.z = p * xs[6]; o1.w = p * xs[7];
  *(float4*)(orow) = o0;
  *(float4*)(orow + 4) = o1;
  uint4 xw;
  xw.x = (uint32_t)f2bf(xs[0]) | ((uint32_t)f2bf(xs[1]) << 16);
  xw.y = (uint32_t)f2bf(xs[2]) | ((uint32_t)f2bf(xs[3]) << 16);
  xw.z = (uint32_t)f2bf(xs[4]) | ((uint32_t)f2bf(xs[5]) << 16);
  xw.w = (uint32_t)f2bf(xs[6]) | ((uint32_t)f2bf(xs[7]) << 16);
  *(uint4*)(xb + (size_t)t * D_ + seg * 8) = xw;
}

// ======================================================================
// 256x256 / 8-wave / BK=64 GEMM core (T3-minimum schedule at 256^2 geometry)
//   LDS: 2 buffers x (A 32KB + B 32KB) = 128 KB. Linear gl_lds dest;
//   XOR swizzle applied on SOURCE (stage) and READ (both-sides, rule 21):
//   LDS[row][seg] holds global chunk (seg ^ (row&7)); read chunk c at
//   seg = c ^ (row&7). Makes wave b128 reads bank-uniform (conflict-free).
//   Per K-tile: stage next (8 gl_lds/thread) -> compute cur (24 ds_read_b128,
//   64 MFMA per wave, no intra-tile barriers) -> one __syncthreads (drain).
// ======================================================================

// ---------------- GEMM1: h(bf16) = relu(Xb_gathered * WiT^T), tile 256x256
__global__ __launch_bounds__(512, 2) void k_gemm1(const u16* __restrict__ xb,
                                                  const u16* __restrict__ WiT,
                                                  u16* __restrict__ h,
                                                  const int* __restrict__ slot_token,
                                                  const int* __restrict__ cnt,
                                                  int b0, int nb, int e0, int ne) {
  __shared__ __align__(16) u16 L[65536];   // 128 KB: [buf][A 16384 u16 | B 16384 u16]
  int z = blockIdx.z;
  int el = z / nb, bl = z % nb;
  int e = e0 + el, b = b0 + bl;
  int be = b * 8 + e;
  int m_cnt = cnt[be];
  int m0 = blockIdx.y * 256;
  if (m0 >= m_cnt) return;
  int n0 = blockIdx.x * 256;
  int tid = threadIdx.x, w = tid >> 6, l = tid & 63;
  // ---- staging map: issue i covers rows i*64 + w*8 + (l>>3), 16B chunk (l&7)^(l>>3)
  int sub = l >> 3;                // 0..7
  int chunk = (l & 7) ^ sub;       // swizzled source chunk
  const u16* wbase = WiT + (size_t)el * FF_ * D_;
  const u16* gA[4]; const u16* gB[4];
#pragma unroll
  for (int i = 0; i < 4; i++) {
    int row = i * 64 + w * 8 + sub;
    int ia = m0 + row; if (ia >= m_cnt) ia = m_cnt - 1;
    int t = slot_token[be * C_ + ia] & (S_ - 1);
    gA[i] = xb + (size_t)(b * S_ + t) * D_ + chunk * 8;
    gB[i] = wbase + (size_t)(n0 + row) * D_ + chunk * 8;
  }
  int sdst = w * 512 + l * 8;      // u16; per-issue += 4096; dest is linear
  // ---- accumulators
  v4f acc[8][4];
#pragma unroll
  for (int mi = 0; mi < 8; mi++)
#pragma unroll
    for (int ni = 0; ni < 4; ni++) acc[mi][ni] = (v4f){0.f, 0.f, 0.f, 0.f};
  // ---- read map
  int wm = w >> 2, wn = w & 3;     // wave grid 2M x 4N, per-wave 128x64
  int lr = l & 15, q = l >> 4, r7 = lr & 7;
  int aoff[8], boff[4];
#pragma unroll
  for (int mf = 0; mf < 8; mf++) aoff[mf] = (wm * 128 + mf * 16 + lr) * 64;
#pragma unroll
  for (int nf = 0; nf < 4; nf++) boff[nf] = 16384 + (wn * 64 + nf * 16 + lr) * 64;
  // ---- prologue: stage K-tile 0 into buf0
#pragma unroll
  for (int i = 0; i < 4; i++) {
    gl_lds16(gA[i], &L[sdst + i * 4096]);          gA[i] += 64;
    gl_lds16(gB[i], &L[16384 + sdst + i * 4096]);  gB[i] += 64;
  }
  __syncthreads();
  int cur = 0;
  const int NT = D_ / 64;          // 12 K-tiles
  for (int t = 0; t < NT; t++) {
    if (t + 1 < NT) {              // stage next into alt buffer
      int ab = (cur ^ 1) * 32768;
#pragma unroll
      for (int i = 0; i < 4; i++) {
        gl_lds16(gA[i], &L[ab + sdst + i * 4096]);          gA[i] += 64;
        gl_lds16(gB[i], &L[ab + 16384 + sdst + i * 4096]);  gB[i] += 64;
      }
    }
    int cb = cur * 32768;
#pragma unroll
    for (int kh = 0; kh < 2; kh++) {
      int cA = (((kh * 4 + q) ^ r7) << 3);
      bf8v bfr[4];
#pragma unroll
      for (int nf = 0; nf < 4; nf++) bfr[nf] = *(const bf8v*)&L[cb + boff[nf] + cA];
#pragma unroll
      for (int mh = 0; mh < 2; mh++) {
        bf8v afr[4];
#pragma unroll
        for (int j = 0; j < 4; j++) afr[j] = *(const bf8v*)&L[cb + aoff[mh * 4 + j] + cA];
#pragma unroll
        for (int j = 0; j < 4; j++)
#pragma unroll
          for (int nf = 0; nf < 4; nf++)
            acc[mh * 4 + j][nf] =
                __builtin_amdgcn_mfma_f32_16x16x32_bf16(afr[j], bfr[nf], acc[mh * 4 + j][nf], 0, 0, 0);
      }
    }
    __syncthreads();               // drains vmcnt(0): alt ready; cur reads done
    cur ^= 1;
  }
  size_t hb = (size_t)(el * nb + bl) * C_ * FF_;
#pragma unroll
  for (int mi = 0; mi < 8; mi++) {
#pragma unroll
    for (int r = 0; r < 4; r++) {
      int row = m0 + wm * 128 + mi * 16 + q * 4 + r;
      if (row < C_) {
        u16* hr = h + hb + (size_t)row * FF_ + n0 + wn * 64 + lr;
#pragma unroll
        for (int ni = 0; ni < 4; ni++) {
          float v = acc[mi][ni][r];
          hr[ni * 16] = f2bf(v > 0.f ? v : 0.f);
        }
      }
    }
  }
}

// ---------------- GEMM2: scatter fp32 rows p * (h * WoT^T) into out, tile 256x256
__global__ __launch_bounds__(512, 2) void k_gemm2(const u16* __restrict__ h,
                                                  const u16* __restrict__ WoT,
                                                  float* __restrict__ out,
                                                  const int* __restrict__ slot_token,
                                                  const int* __restrict__ cnt,
                                                  const float* __restrict__ prob_max,
                                                  int b0, int nb, int e0, int ne) {
  __shared__ __align__(16) u16 L[65536];
  int z = blockIdx.z;
  int el = z / nb, bl = z % nb;
  int e = e0 + el, b = b0 + bl;
  int be = b * 8 + e;
  int m_cnt = cnt[be];
  int m0 = blockIdx.y * 256;
  if (m0 >= m_cnt) return;
  int n0 = blockIdx.x * 256;
  int tid = threadIdx.x, w = tid >> 6, l = tid & 63;
  int sub = l >> 3;
  int chunk = (l & 7) ^ sub;
  size_t hb = (size_t)(el * nb + bl) * C_ * FF_;
  const u16* wbase = WoT + (size_t)el * D_ * FF_;
  const u16* gA[4]; const u16* gB[4];
#pragma unroll
  for (int i = 0; i < 4; i++) {
    int row = i * 64 + w * 8 + sub;
    int ia = m0 + row; if (ia >= m_cnt) ia = m_cnt - 1;
    gA[i] = h + hb + (size_t)ia * FF_ + chunk * 8;
    gB[i] = wbase + (size_t)(n0 + row) * FF_ + chunk * 8;
  }
  int sdst = w * 512 + l * 8;
  v4f acc[8][4];
#pragma unroll
  for (int mi = 0; mi < 8; mi++)
#pragma unroll
    for (int ni = 0; ni < 4; ni++) acc[mi][ni] = (v4f){0.f, 0.f, 0.f, 0.f};
  int wm = w >> 2, wn = w & 3;
  int lr = l & 15, q = l >> 4, r7 = lr & 7;
  int aoff[8], boff[4];
#pragma unroll
  for (int mf = 0; mf < 8; mf++) aoff[mf] = (wm * 128 + mf * 16 + lr) * 64;
#pragma unroll
  for (int nf = 0; nf < 4; nf++) boff[nf] = 16384 + (wn * 64 + nf * 16 + lr) * 64;
#pragma unroll
  for (int i = 0; i < 4; i++) {
    gl_lds16(gA[i], &L[sdst + i * 4096]);          gA[i] += 64;
    gl_lds16(gB[i], &L[16384 + sdst + i * 4096]);  gB[i] += 64;
  }
  __syncthreads();
  int cur = 0;
  const int NT = FF_ / 64;         // 48 K-tiles
  for (int t = 0; t < NT; t++) {
    if (t + 1 < NT) {
      int ab = (cur ^ 1) * 32768;
#pragma unroll
      for (int i = 0; i < 4; i++) {
        gl_lds16(gA[i], &L[ab + sdst + i * 4096]);          gA[i] += 64;
        gl_lds16(gB[i], &L[ab + 16384 + sdst + i * 4096]);  gB[i] += 64;
      }
    }
    int cb = cur * 32768;
#pragma unroll
    for (int kh = 0; kh < 2; kh++) {
      int cA = (((kh * 4 + q) ^ r7) << 3);
      bf8v bfr[4];
#pragma unroll
      for (int nf = 0; nf < 4; nf++) bfr[nf] = *(const bf8v*)&L[cb + boff[nf] + cA];
#pragma unroll
      for (int mh = 0; mh < 2; mh++) {
        bf8v afr[4];
#pragma unroll
        for (int j = 0; j < 4; j++) afr[j] = *(const bf8v*)&L[cb + aoff[mh * 4 + j] + cA];
#pragma unroll
        for (int j = 0; j < 4; j++)
#pragma unroll
          for (int nf = 0; nf < 4; nf++)
            acc[mh * 4 + j][nf] =
                __builtin_amdgcn_mfma_f32_16x16x32_bf16(afr[j], bfr[nf], acc[mh * 4 + j][nf], 0, 0, 0);
      }
    }
    __syncthreads();
    cur ^= 1;
  }
#pragma unroll
  for (int mi = 0; mi < 8; mi++) {
#pragma unroll
    for (int r = 0; r < 4; r++) {
      int row = m0 + wm * 128 + mi * 16 + q * 4 + r;
      if (row < m_cnt) {
        int tok = slot_token[be * C_ + row] & (S_ - 1);
        float p = prob_max[b * S_ + tok];
        float* orow = out + (size_t)(b * S_ + tok) * D_ + n0 + wn * 64 + lr;
#pragma unroll
        for (int ni = 0; ni < 4; ni++)
          orow[ni * 16] = acc[mi][ni][r] * p;
      }
    }
  }
}

extern "C" void kernel_launch(void* const* d_in, const int* in_sizes, int n_in,
                              void* d_out, int out_size, void* d_ws, size_t ws_size,
                              hipStream_t stream) {
  const float* x  = (const float*)d_in[0];
  const float* Wr = (const float*)d_in[1];
  const float* Wi = (const float*)d_in[2];
  const float* Wo = (const float*)d_in[3];
  float* out = (float*)d_out;
  float* logits_out = out + (size_t)B_ * S_ * D_;
  float* idx_out = logits_out + (size_t)B_ * S_ * E_;

  char* ws = (char*)d_ws;
  float* prob_max   = (float*)(ws);             // 65,536 B
  int*   expert_idx = (int*)(ws + 65536);       // 65,536 B
  int*   slot_token = (int*)(ws + 131072);      // 98,304 B
  int*   cnt        = (int*)(ws + 229376);      // 256 B
  u16*   xb         = (u16*)(ws + 229632);      // 25,165,824 B (bf16 copy of x)
  const size_t chunk0 = 25395456ull;

  const int cand_ne[7] = {8, 4, 2, 1, 1, 1, 1};
  const int cand_nb[7] = {8, 8, 8, 8, 4, 2, 1};
  int ne = 1, nb = 1;
  for (int i = 0; i < 7; i++) {
    size_t need = chunk0 + (size_t)cand_ne[i] * 9437184ull
                + (size_t)cand_ne[i] * cand_nb[i] * 2359296ull;
    if (need <= ws_size) { ne = cand_ne[i]; nb = cand_nb[i]; break; }
  }
  u16* WiT = (u16*)(ws + chunk0);               // ne * 4,718,592 B
  u16* WoT = WiT + (size_t)ne * FF_ * D_;       // ne * 4,718,592 B
  u16* h   = WoT + (size_t)ne * D_ * FF_;       // ne * nb * 2,359,296 B

  k_router<<<dim3(4096), 256, 0, stream>>>(x, Wr, logits_out, prob_max, expert_idx);
  k_scan<<<dim3(64), 256, 0, stream>>>(expert_idx, slot_token, cnt, idx_out);
  k_init_out<<<dim3(6144), 256, 0, stream>>>(x, prob_max, out, xb);
  for (int e0 = 0; e0 < E_; e0 += ne) {
    k_transpose<<<dim3(48, 12, 2 * ne), 256, 0, stream>>>(Wi, Wo, WiT, WoT, e0, ne);
    for (int b0 = 0; b0 < B_; b0 += nb) {
      int zc = nb * ne;
      k_gemm1<<<dim3(12, 2, zc), 512, 0, stream>>>(xb, WiT, h, slot_token, cnt, b0, nb, e0, ne);
      k_gemm2<<<dim3(3, 2, zc), 512, 0, stream>>>(h, WoT, out, slot_token, cnt, prob_max, b0, nb, e0, ne);
    }
  }
}